// Round 12
// baseline (563.506 us; speedup 1.0000x reference)
//
#include <hip/hip_runtime.h>
#include <math.h>

typedef __attribute__((ext_vector_type(8))) __bf16 bf16x8;
typedef __attribute__((ext_vector_type(4))) float f32x4;
typedef __attribute__((ext_vector_type(16))) float f32x16;
typedef __attribute__((ext_vector_type(8))) unsigned short u16x8;
typedef __attribute__((ext_vector_type(8))) int i32x8;

#define GAS(p) ((const __attribute__((address_space(1))) void*)(p))
#define LAS(p) ((__attribute__((address_space(3))) void*)(p))

__device__ __forceinline__ unsigned short f2bf(float f) {
  union { float f; unsigned int u; } v; v.f = f;
  unsigned int r = (v.u + 0x7FFFu + ((v.u >> 16) & 1u)) >> 16;
  return (unsigned short)r;
}
__device__ __forceinline__ float bf2f(unsigned short b) {
  union { unsigned int u; float f; } v; v.u = ((unsigned int)b) << 16;
  return v.f;
}

// ---------------- fused f32 -> bf16 cast for z1,z2,w1,w2 ----------------
__global__ __launch_bounds__(256) void cast_all_kernel(
    const float* __restrict__ z1, const float* __restrict__ z2,
    const float* __restrict__ w1, const float* __restrict__ w2,
    unsigned short* __restrict__ z1b, unsigned short* __restrict__ z2b,
    unsigned short* __restrict__ w1b, unsigned short* __restrict__ w2b) {
  int b = blockIdx.x;
  const float* in; unsigned short* out; int base;
  if (b < 4096)       { in = z1; out = z1b; base = b; }
  else if (b < 8192)  { in = z2; out = z2b; base = b - 4096; }
  else if (b < 8448)  { in = w1; out = w1b; base = b - 8192; }
  else                { in = w2; out = w2b; base = b - 8448; }
  int i = (base * 256 + threadIdx.x) * 4;
  float4 v = *(const float4*)(in + i);
  ushort4 o;
  o.x = f2bf(v.x); o.y = f2bf(v.y); o.z = f2bf(v.z); o.w = f2bf(v.w);
  *(ushort4*)(out + i) = o;
}

// ---------------- core 128x128 NT bf16 tile, K=512 (projections) ----------------
__device__ __forceinline__ void gemm_tile_512(
    const unsigned short* __restrict__ A, const unsigned short* __restrict__ B,
    int m0, int n0, unsigned short* lA, unsigned short* lB, f32x4 acc[4][4]) {
  constexpr int K = 512;
  const int tid  = threadIdx.x;
  const int wave = tid >> 6;
  const int lane = tid & 63;
  const int quad = lane >> 4;
  const int l16  = lane & 15;
  const int wrow = (wave & 1) * 64;
  const int wcol = (wave >> 1) * 64;

  const f32x4 zero = {0.f, 0.f, 0.f, 0.f};
#pragma unroll
  for (int i = 0; i < 4; ++i)
#pragma unroll
    for (int j = 0; j < 4; ++j) acc[i][j] = zero;

  const int e0 = wave * 1024 + lane * 8;
  const int r0 = e0 >> 5, c0 = e0 & 31;
  const int e1 = e0 + 512;
  const int r1 = e1 >> 5, c1 = e1 & 31;

  const unsigned short* Ag0 = A + (size_t)(m0 + r0) * K + c0;
  const unsigned short* Ag1 = A + (size_t)(m0 + r1) * K + c1;
  const unsigned short* Bg0 = B + (size_t)(n0 + r0) * K + c0;
  const unsigned short* Bg1 = B + (size_t)(n0 + r1) * K + c1;

  for (int kt = 0; kt < K; kt += 32) {
    __syncthreads();
    __builtin_amdgcn_global_load_lds(GAS(Ag0 + kt), LAS(&lA[e0]), 16, 0, 0);
    __builtin_amdgcn_global_load_lds(GAS(Ag1 + kt), LAS(&lA[e1]), 16, 0, 0);
    __builtin_amdgcn_global_load_lds(GAS(Bg0 + kt), LAS(&lB[e0]), 16, 0, 0);
    __builtin_amdgcn_global_load_lds(GAS(Bg1 + kt), LAS(&lB[e1]), 16, 0, 0);
    __syncthreads();

    bf16x8 af[4], bfr[4];
#pragma unroll
    for (int i = 0; i < 4; ++i) {
      af[i]  = *(const bf16x8*)&lA[(wrow + i * 16 + l16) * 32 + quad * 8];
      bfr[i] = *(const bf16x8*)&lB[(wcol + i * 16 + l16) * 32 + quad * 8];
    }
#pragma unroll
    for (int mi = 0; mi < 4; ++mi)
#pragma unroll
      for (int ni = 0; ni < 4; ++ni)
        acc[mi][ni] = __builtin_amdgcn_mfma_f32_16x16x32_bf16(
            af[mi], bfr[ni], acc[mi][ni], 0, 0, 0);
  }
}

// ---------------- fused projection GEMM (2 inputs per launch) ----------------
template<int EPI>
__global__ __launch_bounds__(256)
void proj_kernel(const unsigned short* __restrict__ A1,
                 const unsigned short* __restrict__ A2,
                 const unsigned short* __restrict__ W,
                 const float* __restrict__ bias,
                 unsigned short* __restrict__ C1,
                 unsigned short* __restrict__ C2) {
  __shared__ unsigned short lA[128 * 32];
  __shared__ unsigned short lB[128 * 32];
  const int b = blockIdx.x;
  const int which = b >> 8;
  const int r = b & 255;
  const int n0 = (r & 3) * 128;
  const int m0 = (r >> 2) * 128;
  const unsigned short* A = which ? A2 : A1;
  unsigned short* C = which ? C2 : C1;

  f32x4 acc[4][4];
  gemm_tile_512(A, W, m0, n0, lA, lB, acc);

  const int lane = threadIdx.x & 63;
  const int wave = threadIdx.x >> 6;
  const int quad = lane >> 4;
  const int l16  = lane & 15;
  const int wrow = (wave & 1) * 64;
  const int wcol = (wave >> 1) * 64;

#pragma unroll
  for (int ni = 0; ni < 4; ++ni) {
    const int c = n0 + wcol + ni * 16 + l16;
    const float bv = bias[c];
#pragma unroll
    for (int mi = 0; mi < 4; ++mi) {
      const int rbase = m0 + wrow + mi * 16 + quad * 4;
#pragma unroll
      for (int rr = 0; rr < 4; ++rr) {
        float v = acc[mi][ni][rr] + bv;
        if constexpr (EPI == 0) v = (v > 0.f) ? v : expm1f(v);
        C[(size_t)(rbase + rr) * 512 + c] = f2bf(v);
      }
    }
  }
}

// ========== 2-row-tile A-resident 32x32x64 MX-fp8 Gram (512 threads) ==========
// Block: 8 waves; rows [R, R+256) (2 row-tiles, 8 fragment-major 32-row panels
// FULLY resident in LDS = 128 KB, staged once) x B col-group of 4 tiles, each
// staged in 4 KT chunks (16 KB) through a 2x16 KB double buffer (stage-ahead:
// issue KT+1 before computing KT, so the barrier drain sits one compute-round
// after issue -- required at 1 block/CU).  Staged bytes: A 64KB/2tiles amortized
// + B 64KB/tile = 48 KB/tile vs R11's 80 -> 401 MB total (0.60x), attacking the
// measured ~6 TB/s staging-delivery ceiling.
// Tri decode: row-pairs p in [0,32), col groups g; C(2m)=m(m+1), C(2m+1)=(m+1)^2.
// XCD mapping: b&7 = XCD; tri views interleaved in opposite p order for balance;
// cross: XCD x owns B col-groups {2x,2x+1} (hot 512 KB in its L2).
__global__ __launch_bounds__(512, 2)
void gram_kernel(const unsigned char* __restrict__ q1,
                 const unsigned char* __restrict__ q2,
                 float* __restrict__ d11, float* __restrict__ d22,
                 float* __restrict__ d12r, float* __restrict__ d12c) {
  extern __shared__ unsigned char lds[];
  unsigned char* lA = lds;             // 8 panels x 16 KB = 131072
  unsigned char* lB = lds + 131072;    // 2 x 16384 double buffer

  const int b = blockIdx.x;
  const unsigned char *Abase, *Bbase;
  float *rptr, *cptr;
  int R, g, cnt;
  bool cross;
  if (b < 544) {
    const int xcd = b & 7, loc = b >> 3;
    const int job = xcd * 68 + loc;
    const bool v2 = (job >= 272);
    const int j = v2 ? (543 - job) : job;
    int p = 0;
    while (p < 31) {
      const int pn = p + 1, m = pn >> 1;
      const int Cn = (pn & 1) ? (m + 1) * (m + 1) : m * (m + 1);
      if (Cn <= j) ++p; else break;
    }
    const int m = p >> 1;
    const int Cp = (p & 1) ? (m + 1) * (m + 1) : m * (m + 1);
    g = j - Cp;
    R = p * 256;
    cnt = min(4, (2 * p + 2) - 4 * g);
    const unsigned char* h = v2 ? q2 : q1;
    Abase = h; Bbase = h;
    rptr = v2 ? d22 : d11; cptr = rptr;
    cross = false;
  } else {
    const int i = b - 544;
    const int xcd = i & 7, loc = i >> 3;
    g = 2 * xcd + (loc >> 5);
    R = (loc & 31) * 256;
    cnt = 4;
    Abase = q1; Bbase = q2;
    rptr = d12r; cptr = d12c;
    cross = true;
  }

  const int wave = threadIdx.x >> 6;
  const int lane = threadIdx.x & 63;
  const int half = lane >> 5;
  const int l31  = lane & 31;
  const int rt_w = (R >> 7) + (wave >> 2);   // this wave's 128-tile row index
  const int lfo  = half * 1024 + l31 * 16;

  // staging addresses
  const unsigned char* Asrc = Abase + (size_t)((R >> 5) + wave) * 16384 + lane * 16;
  unsigned char* Adst = lA + wave * 16384 + lane * 16;
  const int bseg = (wave >> 1) * 4096 + (wave & 1) * 2048 + lane * 16;

  union frag { i32x8 v; int4 h[2]; };

  float rs[16];
#pragma unroll
  for (int rr = 0; rr < 16; ++rr) rs[rr] = 0.f;

  // prologue: B (visit0, KT0) -> buf0 ; A KT0
  {
    const unsigned char* Bs = Bbase + (size_t)(g * 16 + (wave >> 1)) * 16384
                            + (wave & 1) * 2048 + lane * 16;
    __builtin_amdgcn_global_load_lds(GAS(Bs), LAS(lB + bseg), 16, 0, 0);
    __builtin_amdgcn_global_load_lds(GAS(Bs + 1024), LAS(lB + bseg + 1024), 16, 0, 0);
#pragma unroll
    for (int i = 0; i < 4; ++i)
      __builtin_amdgcn_global_load_lds(GAS(Asrc + i * 1024),
                                       LAS(Adst + i * 1024), 16, 0, 0);
  }
  __syncthreads();

  for (int t = 0; t < cnt; ++t) {
    const int ct = g * 4 + t;

    f32x16 acc[4];
#pragma unroll
    for (int ni = 0; ni < 4; ++ni)
#pragma unroll
      for (int rr = 0; rr < 16; ++rr) acc[ni][rr] = 0.f;

#pragma unroll
    for (int KT = 0; KT < 4; ++KT) {
      // stage-ahead: issue next chunk before computing current
      if (KT < 3) {
        const unsigned char* Bs = Bbase + (size_t)(ct * 4 + (wave >> 1)) * 16384
                                + (KT + 1) * 4096 + (wave & 1) * 2048 + lane * 16;
        unsigned char* bd = lB + ((KT + 1) & 1) * 16384 + bseg;
        __builtin_amdgcn_global_load_lds(GAS(Bs), LAS(bd), 16, 0, 0);
        __builtin_amdgcn_global_load_lds(GAS(Bs + 1024), LAS(bd + 1024), 16, 0, 0);
        if (t == 0) {
#pragma unroll
          for (int i = 0; i < 4; ++i)
            __builtin_amdgcn_global_load_lds(
                GAS(Asrc + (KT + 1) * 4096 + i * 1024),
                LAS(Adst + (KT + 1) * 4096 + i * 1024), 16, 0, 0);
        }
      } else if (t + 1 < cnt) {
        const unsigned char* Bs = Bbase + (size_t)((ct + 1) * 4 + (wave >> 1)) * 16384
                                + (wave & 1) * 2048 + lane * 16;
        unsigned char* bd = lB + bseg;   // (KT+1)&1 == 0
        __builtin_amdgcn_global_load_lds(GAS(Bs), LAS(bd), 16, 0, 0);
        __builtin_amdgcn_global_load_lds(GAS(Bs + 1024), LAS(bd + 1024), 16, 0, 0);
      }

      const unsigned char* bufB = lB + (KT & 1) * 16384;
#pragma unroll
      for (int ktl = 0; ktl < 2; ++ktl) {
        frag fa, fb[4];
        const int oa = wave * 16384 + KT * 4096 + ktl * 2048 + lfo;
        fa.h[0] = *(const int4*)&lA[oa];
        fa.h[1] = *(const int4*)&lA[oa + 512];
#pragma unroll
        for (int ni = 0; ni < 4; ++ni) {
          const int ob = ni * 4096 + ktl * 2048 + lfo;
          fb[ni].h[0] = *(const int4*)&bufB[ob];
          fb[ni].h[1] = *(const int4*)&bufB[ob + 512];
        }
#pragma unroll
        for (int ni = 0; ni < 4; ++ni)
          acc[ni] = __builtin_amdgcn_mfma_scale_f32_32x32x64_f8f6f4(
              fa.v, fb[ni].v, acc[ni],
              0, 0,                    // cbsz=e4m3, blgp=e4m3
              0, 0x7F7F7F7F,           // scale_a (E8M0 1.0)
              0, 0x7F7F7F7F);          // scale_b
      }
      __syncthreads();
    }

    // per-visit epilogue (32x32 C/D layout: col=lane&31, row=(r&3)+8*(r>>2)+4*half)
    const bool valid = cross || (ct <= rt_w);
    const bool docol = cross || (ct < rt_w);
    if (valid) {
      float cs[4] = {0.f, 0.f, 0.f, 0.f};
#pragma unroll
      for (int ni = 0; ni < 4; ++ni)
#pragma unroll
        for (int rr = 0; rr < 16; ++rr) {
          const float v = __expf(2.0f * acc[ni][rr]);
          rs[rr] += v;
          cs[ni] += v;
        }
      if (docol) {
#pragma unroll
        for (int ni = 0; ni < 4; ++ni) {
          const float v = cs[ni] + __shfl_xor(cs[ni], 32, 64);
          if (half == 0) atomicAdd(&cptr[ct * 128 + ni * 32 + l31], v);
        }
      }
    }
  }

  // rowsum: butterfly over the 32 column-lanes (d<32 stays within half)
#pragma unroll
  for (int d = 1; d < 32; d <<= 1) {
#pragma unroll
    for (int rr = 0; rr < 16; ++rr) rs[rr] += __shfl_xor(rs[rr], d, 64);
  }
  if (l31 == 0) {
    const int rb = R + wave * 32;
#pragma unroll
    for (int rr = 0; rr < 16; ++rr) {
      const int row = rb + (rr & 3) + 8 * (rr >> 2) + 4 * half;
      atomicAdd(&rptr[row], rs[rr]);
    }
  }
}

// ------- normalize -> fp8 in 32-row-panel FRAGMENT-MAJOR layout + diag dot -------
__global__ __launch_bounds__(256)
void norm_diag_kernel(const unsigned short* __restrict__ h1,
                      const unsigned short* __restrict__ h2,
                      unsigned char* __restrict__ q1,
                      unsigned char* __restrict__ q2,
                      float* __restrict__ cdiag) {
  const int wave = threadIdx.x >> 6, lane = threadIdx.x & 63;
  const int row = blockIdx.x * 4 + wave;
  const u16x8 u1 = *(const u16x8*)(h1 + (size_t)row * 512 + lane * 8);
  const u16x8 u2 = *(const u16x8*)(h2 + (size_t)row * 512 + lane * 8);
  float f1[8], f2[8], ss1 = 0.f, ss2 = 0.f;
#pragma unroll
  for (int j = 0; j < 8; ++j) {
    f1[j] = bf2f(u1[j]); ss1 += f1[j] * f1[j];
    f2[j] = bf2f(u2[j]); ss2 += f2[j] * f2[j];
  }
#pragma unroll
  for (int d = 1; d < 64; d <<= 1) {
    ss1 += __shfl_xor(ss1, d, 64);
    ss2 += __shfl_xor(ss2, d, 64);
  }
  const float inv1 = 1.0f / fmaxf(sqrtf(ss1), 1e-12f);
  const float inv2 = 1.0f / fmaxf(sqrtf(ss2), 1e-12f);
  float a[8], bb[8];
  float dot = 0.f;
#pragma unroll
  for (int j = 0; j < 8; ++j) {
    a[j] = f1[j] * inv1; bb[j] = f2[j] * inv2;
    dot += a[j] * bb[j];
  }
  int lo1 = __builtin_amdgcn_cvt_pk_fp8_f32(a[0], a[1], 0, false);
  lo1 = __builtin_amdgcn_cvt_pk_fp8_f32(a[2], a[3], lo1, true);
  int hi1 = __builtin_amdgcn_cvt_pk_fp8_f32(a[4], a[5], 0, false);
  hi1 = __builtin_amdgcn_cvt_pk_fp8_f32(a[6], a[7], hi1, true);
  int lo2 = __builtin_amdgcn_cvt_pk_fp8_f32(bb[0], bb[1], 0, false);
  lo2 = __builtin_amdgcn_cvt_pk_fp8_f32(bb[2], bb[3], lo2, true);
  int hi2 = __builtin_amdgcn_cvt_pk_fp8_f32(bb[4], bb[5], 0, false);
  hi2 = __builtin_amdgcn_cvt_pk_fp8_f32(bb[6], bb[7], hi2, true);

  // fragment-major dst: panel = row>>5, 64-col chunk = c0>>6, sub = (c0>>4)&3
  const int c0 = lane * 8;
  const size_t dst = (size_t)(row >> 5) * 16384 + (c0 >> 6) * 2048
                   + ((c0 >> 4) & 3) * 512 + (row & 31) * 16 + (c0 & 15);
  *(int2*)(q1 + dst) = make_int2(lo1, hi1);
  *(int2*)(q2 + dst) = make_int2(lo2, hi2);
#pragma unroll
  for (int d = 1; d < 64; d <<= 1) dot += __shfl_xor(dot, d, 64);
  if (lane == 0) cdiag[row] = dot;
}

// ---------------- final scalar loss ----------------
__global__ __launch_bounds__(256)
void finalize_kernel(const float* __restrict__ d11, const float* __restrict__ d22,
                     const float* __restrict__ d12r, const float* __restrict__ d12c,
                     const float* __restrict__ cdiag, float* __restrict__ out) {
  const float e2 = 7.38905609893065f;
  float s = 0.f;
  for (int i = threadIdx.x; i < 8192; i += 256) {
    const float den1 = d11[i] + d12r[i] - e2;
    const float den2 = d22[i] + d12c[i] - e2;
    s += -2.0f * cdiag[i] + 0.5f * (logf(den1) + logf(den2));
  }
#pragma unroll
  for (int d = 1; d < 64; d <<= 1) s += __shfl_xor(s, d, 64);
  __shared__ float sm[4];
  if ((threadIdx.x & 63) == 0) sm[threadIdx.x >> 6] = s;
  __syncthreads();
  if (threadIdx.x == 0) out[0] = (sm[0] + sm[1] + sm[2] + sm[3]) * (1.0f / 8192.0f);
}

extern "C" void kernel_launch(void* const* d_in, const int* in_sizes, int n_in,
                              void* d_out, int out_size, void* d_ws, size_t ws_size,
                              hipStream_t stream) {
  const float* z1 = (const float*)d_in[0];
  const float* z2 = (const float*)d_in[1];
  const float* w1 = (const float*)d_in[2];
  const float* b1 = (const float*)d_in[3];
  const float* w2 = (const float*)d_in[4];
  const float* b2 = (const float*)d_in[5];
  float* out = (float*)d_out;

  const int N = 8192, D = 512;
  char* ws = (char*)d_ws;
  auto alloc = [&](size_t bytes) {
    char* p = ws; ws += (bytes + 255) & ~(size_t)255; return p;
  };
  unsigned short* z1b = (unsigned short*)alloc((size_t)N * D * 2);
  unsigned short* z2b = (unsigned short*)alloc((size_t)N * D * 2);
  unsigned short* g1  = (unsigned short*)alloc((size_t)N * D * 2);
  unsigned short* g2  = (unsigned short*)alloc((size_t)N * D * 2);
  unsigned short* w1b = (unsigned short*)alloc((size_t)D * D * 2);
  unsigned short* w2b = (unsigned short*)alloc((size_t)D * D * 2);
  float* sums  = (float*)alloc((size_t)4 * N * sizeof(float));
  float* cdiag = (float*)alloc((size_t)N * sizeof(float));
  float* d11 = sums, *d22 = sums + N, *d12r = sums + 2 * N, *d12c = sums + 3 * N;
  unsigned short* h1 = z1b;                 // stage-2 out aliases z buffers
  unsigned short* h2 = z2b;
  unsigned char* q1 = (unsigned char*)g1;   // fp8 aliases g (dead after proj2)
  unsigned char* q2 = (unsigned char*)g2;

  hipMemsetAsync(sums, 0, (size_t)4 * N * sizeof(float), stream);

  // allow the gram kernel the full 160 KiB of LDS (dynamic shared)
  hipFuncSetAttribute((const void*)gram_kernel,
                      hipFuncAttributeMaxDynamicSharedMemorySize, 163840);

  cast_all_kernel<<<dim3(8704), 256, 0, stream>>>(z1, z2, w1, w2, z1b, z2b, w1b, w2b);
  proj_kernel<0><<<dim3(512), 256, 0, stream>>>(z1b, z2b, w1b, b1, g1, g2);
  proj_kernel<1><<<dim3(512), 256, 0, stream>>>(g1, g2, w2b, b2, h1, h2);
  norm_diag_kernel<<<dim3(N / 4), 256, 0, stream>>>(h1, h2, q1, q2, cdiag);
  gram_kernel<<<dim3(1056), 512, 163840, stream>>>(q1, q2, d11, d22, d12r, d12c);
  finalize_kernel<<<1, 256, 0, stream>>>(d11, d22, d12r, d12c, cdiag, out);
}

// Round 13
// 562.237 us; speedup vs baseline: 1.0023x; 1.0023x over previous
//
#include <hip/hip_runtime.h>
#include <math.h>

typedef __attribute__((ext_vector_type(8))) __bf16 bf16x8;
typedef __attribute__((ext_vector_type(4))) float f32x4;
typedef __attribute__((ext_vector_type(16))) float f32x16;
typedef __attribute__((ext_vector_type(8))) unsigned short u16x8;
typedef __attribute__((ext_vector_type(8))) int i32x8;

#define GAS(p) ((const __attribute__((address_space(1))) void*)(p))
#define LAS(p) ((__attribute__((address_space(3))) void*)(p))

__device__ __forceinline__ unsigned short f2bf(float f) {
  union { float f; unsigned int u; } v; v.f = f;
  unsigned int r = (v.u + 0x7FFFu + ((v.u >> 16) & 1u)) >> 16;
  return (unsigned short)r;
}
__device__ __forceinline__ float bf2f(unsigned short b) {
  union { unsigned int u; float f; } v; v.u = ((unsigned int)b) << 16;
  return v.f;
}

// ---------------- fused f32 -> bf16 cast for z1,z2,w1,w2 ----------------
__global__ __launch_bounds__(256) void cast_all_kernel(
    const float* __restrict__ z1, const float* __restrict__ z2,
    const float* __restrict__ w1, const float* __restrict__ w2,
    unsigned short* __restrict__ z1b, unsigned short* __restrict__ z2b,
    unsigned short* __restrict__ w1b, unsigned short* __restrict__ w2b) {
  int b = blockIdx.x;
  const float* in; unsigned short* out; int base;
  if (b < 4096)       { in = z1; out = z1b; base = b; }
  else if (b < 8192)  { in = z2; out = z2b; base = b - 4096; }
  else if (b < 8448)  { in = w1; out = w1b; base = b - 8192; }
  else                { in = w2; out = w2b; base = b - 8448; }
  int i = (base * 256 + threadIdx.x) * 4;
  float4 v = *(const float4*)(in + i);
  ushort4 o;
  o.x = f2bf(v.x); o.y = f2bf(v.y); o.z = f2bf(v.z); o.w = f2bf(v.w);
  *(ushort4*)(out + i) = o;
}

// ---------------- core 128x128 NT bf16 tile, K=512 (projections) ----------------
__device__ __forceinline__ void gemm_tile_512(
    const unsigned short* __restrict__ A, const unsigned short* __restrict__ B,
    int m0, int n0, unsigned short* lA, unsigned short* lB, f32x4 acc[4][4]) {
  constexpr int K = 512;
  const int tid  = threadIdx.x;
  const int wave = tid >> 6;
  const int lane = tid & 63;
  const int quad = lane >> 4;
  const int l16  = lane & 15;
  const int wrow = (wave & 1) * 64;
  const int wcol = (wave >> 1) * 64;

  const f32x4 zero = {0.f, 0.f, 0.f, 0.f};
#pragma unroll
  for (int i = 0; i < 4; ++i)
#pragma unroll
    for (int j = 0; j < 4; ++j) acc[i][j] = zero;

  const int e0 = wave * 1024 + lane * 8;
  const int r0 = e0 >> 5, c0 = e0 & 31;
  const int e1 = e0 + 512;
  const int r1 = e1 >> 5, c1 = e1 & 31;

  const unsigned short* Ag0 = A + (size_t)(m0 + r0) * K + c0;
  const unsigned short* Ag1 = A + (size_t)(m0 + r1) * K + c1;
  const unsigned short* Bg0 = B + (size_t)(n0 + r0) * K + c0;
  const unsigned short* Bg1 = B + (size_t)(n0 + r1) * K + c1;

  for (int kt = 0; kt < K; kt += 32) {
    __syncthreads();
    __builtin_amdgcn_global_load_lds(GAS(Ag0 + kt), LAS(&lA[e0]), 16, 0, 0);
    __builtin_amdgcn_global_load_lds(GAS(Ag1 + kt), LAS(&lA[e1]), 16, 0, 0);
    __builtin_amdgcn_global_load_lds(GAS(Bg0 + kt), LAS(&lB[e0]), 16, 0, 0);
    __builtin_amdgcn_global_load_lds(GAS(Bg1 + kt), LAS(&lB[e1]), 16, 0, 0);
    __syncthreads();

    bf16x8 af[4], bfr[4];
#pragma unroll
    for (int i = 0; i < 4; ++i) {
      af[i]  = *(const bf16x8*)&lA[(wrow + i * 16 + l16) * 32 + quad * 8];
      bfr[i] = *(const bf16x8*)&lB[(wcol + i * 16 + l16) * 32 + quad * 8];
    }
#pragma unroll
    for (int mi = 0; mi < 4; ++mi)
#pragma unroll
      for (int ni = 0; ni < 4; ++ni)
        acc[mi][ni] = __builtin_amdgcn_mfma_f32_16x16x32_bf16(
            af[mi], bfr[ni], acc[mi][ni], 0, 0, 0);
  }
}

// ---------------- fused projection GEMM (2 inputs per launch) ----------------
template<int EPI>
__global__ __launch_bounds__(256)
void proj_kernel(const unsigned short* __restrict__ A1,
                 const unsigned short* __restrict__ A2,
                 const unsigned short* __restrict__ W,
                 const float* __restrict__ bias,
                 unsigned short* __restrict__ C1,
                 unsigned short* __restrict__ C2) {
  __shared__ unsigned short lA[128 * 32];
  __shared__ unsigned short lB[128 * 32];
  const int b = blockIdx.x;
  const int which = b >> 8;
  const int r = b & 255;
  const int n0 = (r & 3) * 128;
  const int m0 = (r >> 2) * 128;
  const unsigned short* A = which ? A2 : A1;
  unsigned short* C = which ? C2 : C1;

  f32x4 acc[4][4];
  gemm_tile_512(A, W, m0, n0, lA, lB, acc);

  const int lane = threadIdx.x & 63;
  const int wave = threadIdx.x >> 6;
  const int quad = lane >> 4;
  const int l16  = lane & 15;
  const int wrow = (wave & 1) * 64;
  const int wcol = (wave >> 1) * 64;

#pragma unroll
  for (int ni = 0; ni < 4; ++ni) {
    const int c = n0 + wcol + ni * 16 + l16;
    const float bv = bias[c];
#pragma unroll
    for (int mi = 0; mi < 4; ++mi) {
      const int rbase = m0 + wrow + mi * 16 + quad * 4;
#pragma unroll
      for (int rr = 0; rr < 4; ++rr) {
        float v = acc[mi][ni][rr] + bv;
        if constexpr (EPI == 0) v = (v > 0.f) ? v : expm1f(v);
        C[(size_t)(rbase + rr) * 512 + c] = f2bf(v);
      }
    }
  }
}

// ========== 2-row-tile A-resident 32x32x64 MX-fp8 Gram (512 threads) ==========
// IDENTICAL algorithm to R12 (HW-verified correct: absmax=0) with ONE change:
// __launch_bounds__(512, 1).  R12's (512,2) was honored as 2 blocks/CU ->
// 4 waves/SIMD -> 128-VGPR cap -> 893 MB of scratch spills (the 4x regression).
// (512,1): 1 block/CU, 2 waves/SIMD, 256-reg budget; live set ~135 regs, no
// spills.  Staged bytes 405 MB at the measured ~6 TB/s delivery ceiling
// -> ~67 us floor; stage-ahead B double-buffer hides the barrier drain.
__global__ __launch_bounds__(512, 1)
void gram_kernel(const unsigned char* __restrict__ q1,
                 const unsigned char* __restrict__ q2,
                 float* __restrict__ d11, float* __restrict__ d22,
                 float* __restrict__ d12r, float* __restrict__ d12c) {
  extern __shared__ unsigned char lds[];
  unsigned char* lA = lds;             // 8 panels x 16 KB = 131072
  unsigned char* lB = lds + 131072;    // 2 x 16384 double buffer

  const int b = blockIdx.x;
  const unsigned char *Abase, *Bbase;
  float *rptr, *cptr;
  int R, g, cnt;
  bool cross;
  if (b < 544) {
    const int xcd = b & 7, loc = b >> 3;
    const int job = xcd * 68 + loc;
    const bool v2 = (job >= 272);
    const int j = v2 ? (543 - job) : job;
    int p = 0;
    while (p < 31) {
      const int pn = p + 1, m = pn >> 1;
      const int Cn = (pn & 1) ? (m + 1) * (m + 1) : m * (m + 1);
      if (Cn <= j) ++p; else break;
    }
    const int m = p >> 1;
    const int Cp = (p & 1) ? (m + 1) * (m + 1) : m * (m + 1);
    g = j - Cp;
    R = p * 256;
    cnt = min(4, (2 * p + 2) - 4 * g);
    const unsigned char* h = v2 ? q2 : q1;
    Abase = h; Bbase = h;
    rptr = v2 ? d22 : d11; cptr = rptr;
    cross = false;
  } else {
    const int i = b - 544;
    const int xcd = i & 7, loc = i >> 3;
    g = 2 * xcd + (loc >> 5);
    R = (loc & 31) * 256;
    cnt = 4;
    Abase = q1; Bbase = q2;
    rptr = d12r; cptr = d12c;
    cross = true;
  }

  const int wave = threadIdx.x >> 6;
  const int lane = threadIdx.x & 63;
  const int half = lane >> 5;
  const int l31  = lane & 31;
  const int rt_w = (R >> 7) + (wave >> 2);   // this wave's 128-tile row index
  const int lfo  = half * 1024 + l31 * 16;

  // staging addresses
  const unsigned char* Asrc = Abase + (size_t)((R >> 5) + wave) * 16384 + lane * 16;
  unsigned char* Adst = lA + wave * 16384 + lane * 16;
  const int bseg = (wave >> 1) * 4096 + (wave & 1) * 2048 + lane * 16;

  union frag { i32x8 v; int4 h[2]; };

  float rs[16];
#pragma unroll
  for (int rr = 0; rr < 16; ++rr) rs[rr] = 0.f;

  // prologue: B (visit0, KT0) -> buf0 ; A KT0
  {
    const unsigned char* Bs = Bbase + (size_t)(g * 16 + (wave >> 1)) * 16384
                            + (wave & 1) * 2048 + lane * 16;
    __builtin_amdgcn_global_load_lds(GAS(Bs), LAS(lB + bseg), 16, 0, 0);
    __builtin_amdgcn_global_load_lds(GAS(Bs + 1024), LAS(lB + bseg + 1024), 16, 0, 0);
#pragma unroll
    for (int i = 0; i < 4; ++i)
      __builtin_amdgcn_global_load_lds(GAS(Asrc + i * 1024),
                                       LAS(Adst + i * 1024), 16, 0, 0);
  }
  __syncthreads();

  for (int t = 0; t < cnt; ++t) {
    const int ct = g * 4 + t;

    f32x16 acc[4];
#pragma unroll
    for (int ni = 0; ni < 4; ++ni)
#pragma unroll
      for (int rr = 0; rr < 16; ++rr) acc[ni][rr] = 0.f;

#pragma unroll
    for (int KT = 0; KT < 4; ++KT) {
      // stage-ahead: issue next chunk before computing current
      if (KT < 3) {
        const unsigned char* Bs = Bbase + (size_t)(ct * 4 + (wave >> 1)) * 16384
                                + (KT + 1) * 4096 + (wave & 1) * 2048 + lane * 16;
        unsigned char* bd = lB + ((KT + 1) & 1) * 16384 + bseg;
        __builtin_amdgcn_global_load_lds(GAS(Bs), LAS(bd), 16, 0, 0);
        __builtin_amdgcn_global_load_lds(GAS(Bs + 1024), LAS(bd + 1024), 16, 0, 0);
        if (t == 0) {
#pragma unroll
          for (int i = 0; i < 4; ++i)
            __builtin_amdgcn_global_load_lds(
                GAS(Asrc + (KT + 1) * 4096 + i * 1024),
                LAS(Adst + (KT + 1) * 4096 + i * 1024), 16, 0, 0);
        }
      } else if (t + 1 < cnt) {
        const unsigned char* Bs = Bbase + (size_t)((ct + 1) * 4 + (wave >> 1)) * 16384
                                + (wave & 1) * 2048 + lane * 16;
        unsigned char* bd = lB + bseg;   // (KT+1)&1 == 0
        __builtin_amdgcn_global_load_lds(GAS(Bs), LAS(bd), 16, 0, 0);
        __builtin_amdgcn_global_load_lds(GAS(Bs + 1024), LAS(bd + 1024), 16, 0, 0);
      }

      const unsigned char* bufB = lB + (KT & 1) * 16384;
#pragma unroll
      for (int ktl = 0; ktl < 2; ++ktl) {
        frag fa, fb[4];
        const int oa = wave * 16384 + KT * 4096 + ktl * 2048 + lfo;
        fa.h[0] = *(const int4*)&lA[oa];
        fa.h[1] = *(const int4*)&lA[oa + 512];
#pragma unroll
        for (int ni = 0; ni < 4; ++ni) {
          const int ob = ni * 4096 + ktl * 2048 + lfo;
          fb[ni].h[0] = *(const int4*)&bufB[ob];
          fb[ni].h[1] = *(const int4*)&bufB[ob + 512];
        }
#pragma unroll
        for (int ni = 0; ni < 4; ++ni)
          acc[ni] = __builtin_amdgcn_mfma_scale_f32_32x32x64_f8f6f4(
              fa.v, fb[ni].v, acc[ni],
              0, 0,                    // cbsz=e4m3, blgp=e4m3
              0, 0x7F7F7F7F,           // scale_a (E8M0 1.0)
              0, 0x7F7F7F7F);          // scale_b
      }
      __syncthreads();
    }

    // per-visit epilogue (32x32 C/D layout: col=lane&31, row=(r&3)+8*(r>>2)+4*half)
    const bool valid = cross || (ct <= rt_w);
    const bool docol = cross || (ct < rt_w);
    if (valid) {
      float cs[4] = {0.f, 0.f, 0.f, 0.f};
#pragma unroll
      for (int ni = 0; ni < 4; ++ni)
#pragma unroll
        for (int rr = 0; rr < 16; ++rr) {
          const float v = __expf(2.0f * acc[ni][rr]);
          rs[rr] += v;
          cs[ni] += v;
        }
      if (docol) {
#pragma unroll
        for (int ni = 0; ni < 4; ++ni) {
          const float v = cs[ni] + __shfl_xor(cs[ni], 32, 64);
          if (half == 0) atomicAdd(&cptr[ct * 128 + ni * 32 + l31], v);
        }
      }
    }
  }

  // rowsum: butterfly over the 32 column-lanes (d<32 stays within half)
#pragma unroll
  for (int d = 1; d < 32; d <<= 1) {
#pragma unroll
    for (int rr = 0; rr < 16; ++rr) rs[rr] += __shfl_xor(rs[rr], d, 64);
  }
  if (l31 == 0) {
    const int rb = R + wave * 32;
#pragma unroll
    for (int rr = 0; rr < 16; ++rr) {
      const int row = rb + (rr & 3) + 8 * (rr >> 2) + 4 * half;
      atomicAdd(&rptr[row], rs[rr]);
    }
  }
}

// ------- normalize -> fp8 in 32-row-panel FRAGMENT-MAJOR layout + diag dot -------
__global__ __launch_bounds__(256)
void norm_diag_kernel(const unsigned short* __restrict__ h1,
                      const unsigned short* __restrict__ h2,
                      unsigned char* __restrict__ q1,
                      unsigned char* __restrict__ q2,
                      float* __restrict__ cdiag) {
  const int wave = threadIdx.x >> 6, lane = threadIdx.x & 63;
  const int row = blockIdx.x * 4 + wave;
  const u16x8 u1 = *(const u16x8*)(h1 + (size_t)row * 512 + lane * 8);
  const u16x8 u2 = *(const u16x8*)(h2 + (size_t)row * 512 + lane * 8);
  float f1[8], f2[8], ss1 = 0.f, ss2 = 0.f;
#pragma unroll
  for (int j = 0; j < 8; ++j) {
    f1[j] = bf2f(u1[j]); ss1 += f1[j] * f1[j];
    f2[j] = bf2f(u2[j]); ss2 += f2[j] * f2[j];
  }
#pragma unroll
  for (int d = 1; d < 64; d <<= 1) {
    ss1 += __shfl_xor(ss1, d, 64);
    ss2 += __shfl_xor(ss2, d, 64);
  }
  const float inv1 = 1.0f / fmaxf(sqrtf(ss1), 1e-12f);
  const float inv2 = 1.0f / fmaxf(sqrtf(ss2), 1e-12f);
  float a[8], bb[8];
  float dot = 0.f;
#pragma unroll
  for (int j = 0; j < 8; ++j) {
    a[j] = f1[j] * inv1; bb[j] = f2[j] * inv2;
    dot += a[j] * bb[j];
  }
  int lo1 = __builtin_amdgcn_cvt_pk_fp8_f32(a[0], a[1], 0, false);
  lo1 = __builtin_amdgcn_cvt_pk_fp8_f32(a[2], a[3], lo1, true);
  int hi1 = __builtin_amdgcn_cvt_pk_fp8_f32(a[4], a[5], 0, false);
  hi1 = __builtin_amdgcn_cvt_pk_fp8_f32(a[6], a[7], hi1, true);
  int lo2 = __builtin_amdgcn_cvt_pk_fp8_f32(bb[0], bb[1], 0, false);
  lo2 = __builtin_amdgcn_cvt_pk_fp8_f32(bb[2], bb[3], lo2, true);
  int hi2 = __builtin_amdgcn_cvt_pk_fp8_f32(bb[4], bb[5], 0, false);
  hi2 = __builtin_amdgcn_cvt_pk_fp8_f32(bb[6], bb[7], hi2, true);

  // fragment-major dst: panel = row>>5, 64-col chunk = c0>>6, sub = (c0>>4)&3
  const int c0 = lane * 8;
  const size_t dst = (size_t)(row >> 5) * 16384 + (c0 >> 6) * 2048
                   + ((c0 >> 4) & 3) * 512 + (row & 31) * 16 + (c0 & 15);
  *(int2*)(q1 + dst) = make_int2(lo1, hi1);
  *(int2*)(q2 + dst) = make_int2(lo2, hi2);
#pragma unroll
  for (int d = 1; d < 64; d <<= 1) dot += __shfl_xor(dot, d, 64);
  if (lane == 0) cdiag[row] = dot;
}

// ---------------- final scalar loss ----------------
__global__ __launch_bounds__(256)
void finalize_kernel(const float* __restrict__ d11, const float* __restrict__ d22,
                     const float* __restrict__ d12r, const float* __restrict__ d12c,
                     const float* __restrict__ cdiag, float* __restrict__ out) {
  const float e2 = 7.38905609893065f;
  float s = 0.f;
  for (int i = threadIdx.x; i < 8192; i += 256) {
    const float den1 = d11[i] + d12r[i] - e2;
    const float den2 = d22[i] + d12c[i] - e2;
    s += -2.0f * cdiag[i] + 0.5f * (logf(den1) + logf(den2));
  }
#pragma unroll
  for (int d = 1; d < 64; d <<= 1) s += __shfl_xor(s, d, 64);
  __shared__ float sm[4];
  if ((threadIdx.x & 63) == 0) sm[threadIdx.x >> 6] = s;
  __syncthreads();
  if (threadIdx.x == 0) out[0] = (sm[0] + sm[1] + sm[2] + sm[3]) * (1.0f / 8192.0f);
}

extern "C" void kernel_launch(void* const* d_in, const int* in_sizes, int n_in,
                              void* d_out, int out_size, void* d_ws, size_t ws_size,
                              hipStream_t stream) {
  const float* z1 = (const float*)d_in[0];
  const float* z2 = (const float*)d_in[1];
  const float* w1 = (const float*)d_in[2];
  const float* b1 = (const float*)d_in[3];
  const float* w2 = (const float*)d_in[4];
  const float* b2 = (const float*)d_in[5];
  float* out = (float*)d_out;

  const int N = 8192, D = 512;
  char* ws = (char*)d_ws;
  auto alloc = [&](size_t bytes) {
    char* p = ws; ws += (bytes + 255) & ~(size_t)255; return p;
  };
  unsigned short* z1b = (unsigned short*)alloc((size_t)N * D * 2);
  unsigned short* z2b = (unsigned short*)alloc((size_t)N * D * 2);
  unsigned short* g1  = (unsigned short*)alloc((size_t)N * D * 2);
  unsigned short* g2  = (unsigned short*)alloc((size_t)N * D * 2);
  unsigned short* w1b = (unsigned short*)alloc((size_t)D * D * 2);
  unsigned short* w2b = (unsigned short*)alloc((size_t)D * D * 2);
  float* sums  = (float*)alloc((size_t)4 * N * sizeof(float));
  float* cdiag = (float*)alloc((size_t)N * sizeof(float));
  float* d11 = sums, *d22 = sums + N, *d12r = sums + 2 * N, *d12c = sums + 3 * N;
  unsigned short* h1 = z1b;                 // stage-2 out aliases z buffers
  unsigned short* h2 = z2b;
  unsigned char* q1 = (unsigned char*)g1;   // fp8 aliases g (dead after proj2)
  unsigned char* q2 = (unsigned char*)g2;

  hipMemsetAsync(sums, 0, (size_t)4 * N * sizeof(float), stream);

  // allow the gram kernel the full 160 KiB of LDS (dynamic shared)
  hipFuncSetAttribute((const void*)gram_kernel,
                      hipFuncAttributeMaxDynamicSharedMemorySize, 163840);

  cast_all_kernel<<<dim3(8704), 256, 0, stream>>>(z1, z2, w1, w2, z1b, z2b, w1b, w2b);
  proj_kernel<0><<<dim3(512), 256, 0, stream>>>(z1b, z2b, w1b, b1, g1, g2);
  proj_kernel<1><<<dim3(512), 256, 0, stream>>>(g1, g2, w2b, b2, h1, h2);
  norm_diag_kernel<<<dim3(N / 4), 256, 0, stream>>>(h1, h2, q1, q2, cdiag);
  gram_kernel<<<dim3(1056), 512, 163840, stream>>>(q1, q2, d11, d22, d12r, d12c);
  finalize_kernel<<<1, 256, 0, stream>>>(d11, d22, d12r, d12c, cdiag, out);
}

// Round 14
// 313.782 us; speedup vs baseline: 1.7959x; 1.7918x over previous
//
#include <hip/hip_runtime.h>
#include <math.h>

typedef __attribute__((ext_vector_type(8))) __bf16 bf16x8;
typedef __attribute__((ext_vector_type(4))) float f32x4;
typedef __attribute__((ext_vector_type(16))) float f32x16;
typedef __attribute__((ext_vector_type(8))) unsigned short u16x8;
typedef __attribute__((ext_vector_type(8))) int i32x8;

#define GAS(p) ((const __attribute__((address_space(1))) void*)(p))
#define LAS(p) ((__attribute__((address_space(3))) void*)(p))

__device__ __forceinline__ unsigned short f2bf(float f) {
  union { float f; unsigned int u; } v; v.f = f;
  unsigned int r = (v.u + 0x7FFFu + ((v.u >> 16) & 1u)) >> 16;
  return (unsigned short)r;
}
__device__ __forceinline__ float bf2f(unsigned short b) {
  union { unsigned int u; float f; } v; v.u = ((unsigned int)b) << 16;
  return v.f;
}

// ---------------- f32 -> bf16 cast for w1,w2 only (z fused into proj1) ----------------
__global__ __launch_bounds__(256) void cast_w_kernel(
    const float* __restrict__ w1, const float* __restrict__ w2,
    unsigned short* __restrict__ w1b, unsigned short* __restrict__ w2b) {
  int b = blockIdx.x;
  const float* in; unsigned short* out; int base;
  if (b < 256) { in = w1; out = w1b; base = b; }
  else         { in = w2; out = w2b; base = b - 256; }
  int i = (base * 256 + threadIdx.x) * 4;
  float4 v = *(const float4*)(in + i);
  ushort4 o;
  o.x = f2bf(v.x); o.y = f2bf(v.y); o.z = f2bf(v.z); o.w = f2bf(v.w);
  *(ushort4*)(out + i) = o;
}

// ------- core 128x128 NT tile, K=512; A either f32 (cast-on-stage) or bf16 -------
template<bool AF32>
__device__ __forceinline__ void gemm_tile_512x(
    const void* __restrict__ Av, const unsigned short* __restrict__ B,
    int m0, int n0, unsigned short* lA, unsigned short* lB, f32x4 acc[4][4]) {
  constexpr int K = 512;
  const int tid  = threadIdx.x;
  const int wave = tid >> 6;
  const int lane = tid & 63;
  const int quad = lane >> 4;
  const int l16  = lane & 15;
  const int wrow = (wave & 1) * 64;
  const int wcol = (wave >> 1) * 64;

  const f32x4 zero = {0.f, 0.f, 0.f, 0.f};
#pragma unroll
  for (int i = 0; i < 4; ++i)
#pragma unroll
    for (int j = 0; j < 4; ++j) acc[i][j] = zero;

  const int e0 = wave * 1024 + lane * 8;
  const int r0 = e0 >> 5, c0 = e0 & 31;
  const int e1 = e0 + 512;
  const int r1 = e1 >> 5, c1 = e1 & 31;

  const unsigned short* Ab = (const unsigned short*)Av;
  const float*          Af = (const float*)Av;
  const unsigned short* Ag0 = Ab + (size_t)(m0 + r0) * K + c0;
  const unsigned short* Ag1 = Ab + (size_t)(m0 + r1) * K + c1;
  const float*          Af0 = Af + (size_t)(m0 + r0) * K + c0;
  const float*          Af1 = Af + (size_t)(m0 + r1) * K + c1;
  const unsigned short* Bg0 = B + (size_t)(n0 + r0) * K + c0;
  const unsigned short* Bg1 = B + (size_t)(n0 + r1) * K + c1;

  for (int kt = 0; kt < K; kt += 32) {
    __syncthreads();
    if constexpr (AF32) {
      const float4 a0 = *(const float4*)(Af0 + kt);
      const float4 a1 = *(const float4*)(Af0 + kt + 4);
      const float4 b0 = *(const float4*)(Af1 + kt);
      const float4 b1 = *(const float4*)(Af1 + kt + 4);
      u16x8 p0, p1;
      p0[0]=f2bf(a0.x); p0[1]=f2bf(a0.y); p0[2]=f2bf(a0.z); p0[3]=f2bf(a0.w);
      p0[4]=f2bf(a1.x); p0[5]=f2bf(a1.y); p0[6]=f2bf(a1.z); p0[7]=f2bf(a1.w);
      p1[0]=f2bf(b0.x); p1[1]=f2bf(b0.y); p1[2]=f2bf(b0.z); p1[3]=f2bf(b0.w);
      p1[4]=f2bf(b1.x); p1[5]=f2bf(b1.y); p1[6]=f2bf(b1.z); p1[7]=f2bf(b1.w);
      *(u16x8*)&lA[e0] = p0;
      *(u16x8*)&lA[e1] = p1;
    } else {
      __builtin_amdgcn_global_load_lds(GAS(Ag0 + kt), LAS(&lA[e0]), 16, 0, 0);
      __builtin_amdgcn_global_load_lds(GAS(Ag1 + kt), LAS(&lA[e1]), 16, 0, 0);
    }
    __builtin_amdgcn_global_load_lds(GAS(Bg0 + kt), LAS(&lB[e0]), 16, 0, 0);
    __builtin_amdgcn_global_load_lds(GAS(Bg1 + kt), LAS(&lB[e1]), 16, 0, 0);
    __syncthreads();

    bf16x8 af[4], bfr[4];
#pragma unroll
    for (int i = 0; i < 4; ++i) {
      af[i]  = *(const bf16x8*)&lA[(wrow + i * 16 + l16) * 32 + quad * 8];
      bfr[i] = *(const bf16x8*)&lB[(wcol + i * 16 + l16) * 32 + quad * 8];
    }
#pragma unroll
    for (int mi = 0; mi < 4; ++mi)
#pragma unroll
      for (int ni = 0; ni < 4; ++ni)
        acc[mi][ni] = __builtin_amdgcn_mfma_f32_16x16x32_bf16(
            af[mi], bfr[ni], acc[mi][ni], 0, 0, 0);
  }
}

// ---------------- fused projection GEMM (2 inputs per launch) ----------------
// EPI 0: A is f32 (z), cast-on-stage; elu(acc+bias) -> bf16
// EPI 1: A is bf16 (g); acc+bias -> bf16
template<int EPI>
__global__ __launch_bounds__(256)
void proj_kernel(const void* __restrict__ A1,
                 const void* __restrict__ A2,
                 const unsigned short* __restrict__ W,
                 const float* __restrict__ bias,
                 unsigned short* __restrict__ C1,
                 unsigned short* __restrict__ C2) {
  __shared__ unsigned short lA[128 * 32];
  __shared__ unsigned short lB[128 * 32];
  const int b = blockIdx.x;
  const int which = b >> 8;
  const int r = b & 255;
  const int n0 = (r & 3) * 128;
  const int m0 = (r >> 2) * 128;
  const void* A = which ? A2 : A1;
  unsigned short* C = which ? C2 : C1;

  f32x4 acc[4][4];
  gemm_tile_512x<EPI == 0>(A, W, m0, n0, lA, lB, acc);

  const int lane = threadIdx.x & 63;
  const int wave = threadIdx.x >> 6;
  const int quad = lane >> 4;
  const int l16  = lane & 15;
  const int wrow = (wave & 1) * 64;
  const int wcol = (wave >> 1) * 64;

#pragma unroll
  for (int ni = 0; ni < 4; ++ni) {
    const int c = n0 + wcol + ni * 16 + l16;
    const float bv = bias[c];
#pragma unroll
    for (int mi = 0; mi < 4; ++mi) {
      const int rbase = m0 + wrow + mi * 16 + quad * 4;
#pragma unroll
      for (int rr = 0; rr < 4; ++rr) {
        float v = acc[mi][ni][rr] + bv;
        if constexpr (EPI == 0) v = (v > 0.f) ? v : expm1f(v);
        C[(size_t)(rbase + rr) * 512 + c] = f2bf(v);
      }
    }
  }
}

// ========== A-resident grouped 32x32x64 MX-fp8 Gram, STAGE-AHEAD chunks ==========
// R11 base (verified 110 us) with the KT loop re-chunked to 64 cols (8 KB B):
// issue chunk KT+1's staging BEFORE computing chunk KT, so the vmcnt drain at
// the end-of-chunk barrier sits one compute-round (~280 cyc) after issue
// instead of zero (R11 exposed the full load latency 16x per block).
// LDS: A 64 KB resident + B 2 x 8 KB double buffer = 81920 -> 2 blocks/CU.
__global__ __launch_bounds__(256, 2)
void gram_kernel(const unsigned char* __restrict__ q1,
                 const unsigned char* __restrict__ q2,
                 float* __restrict__ d11, float* __restrict__ d22,
                 float* __restrict__ d12r, float* __restrict__ d12c) {
  __shared__ unsigned char lA[65536];     // 4 panels x full K (fragment-major)
  __shared__ unsigned char lB[2][8192];   // 4 panels x one 64-col chunk, x2

  const int b = blockIdx.x;
  const unsigned char *Abase, *Bbase;
  float *rptr, *cptr;
  int by, g, cnt;
  bool cross;
  if (b < 1088) {
    const bool first = (b < 544);
    int j = first ? b : b - 544;
    int q = (int)((sqrtf(2.f * j + 1.f) - 1.f) * 0.5f);
    while (2 * (q + 1) * (q + 2) <= j) ++q;
    while (2 * q * (q + 1) > j) --q;
    const int w = j - 2 * q * (q + 1);
    const int dr = w / (q + 1);
    g = w - dr * (q + 1);
    by = 4 * q + dr;
    const unsigned char* h = first ? q1 : q2;
    Abase = h; Bbase = h;
    rptr = first ? d11 : d22; cptr = rptr;
    cnt = min(4, by + 1 - g * 4);
    cross = false;
  } else {
    const int j = b - 1088;
    g = j >> 6; by = j & 63;
    Abase = q1; Bbase = q2;
    rptr = d12r; cptr = d12c;
    cnt = 4; cross = true;
  }

  const int tid  = threadIdx.x;
  const int wave = tid >> 6;
  const int lane = tid & 63;
  const int half = lane >> 5;
  const int l31  = lane & 31;
  const int pa0 = (wave & 1) * 2;
  const int pb0 = (wave >> 1) * 2;
  const int lfo = half * 1024 + l31 * 16;

  // staging pointers: wave w handles panel w
  const unsigned char* Asrc = Abase + (size_t)(by * 4 + wave) * 16384 + lane * 16;
  unsigned char* Adst = lA + wave * 16384 + lane * 16;

  union frag { i32x8 v; int4 h[2]; };

  float rs[2][16];
#pragma unroll
  for (int mi = 0; mi < 2; ++mi)
#pragma unroll
    for (int rr = 0; rr < 16; ++rr) rs[mi][rr] = 0.f;

  // prologue: A chunk 0, B(tile g*4, chunk 0) -> buf 0
  {
    __builtin_amdgcn_global_load_lds(GAS(Asrc), LAS(Adst), 16, 0, 0);
    __builtin_amdgcn_global_load_lds(GAS(Asrc + 1024), LAS(Adst + 1024), 16, 0, 0);
    const unsigned char* Bs = Bbase + (size_t)(g * 4 * 4 + wave) * 16384 + lane * 16;
    unsigned char* bd = lB[0] + wave * 2048 + lane * 16;
    __builtin_amdgcn_global_load_lds(GAS(Bs), LAS(bd), 16, 0, 0);
    __builtin_amdgcn_global_load_lds(GAS(Bs + 1024), LAS(bd + 1024), 16, 0, 0);
  }
  __syncthreads();

  for (int t = 0; t < cnt; ++t) {
    const int ct = g * 4 + t;

    f32x16 acc[2][2];
#pragma unroll
    for (int i = 0; i < 2; ++i)
#pragma unroll
      for (int jj = 0; jj < 2; ++jj)
#pragma unroll
        for (int rr = 0; rr < 16; ++rr) acc[i][jj][rr] = 0.f;

#pragma unroll
    for (int KT = 0; KT < 8; ++KT) {
      // stage-ahead: issue next chunk BEFORE computing current
      if (t == 0 && KT < 7) {
        __builtin_amdgcn_global_load_lds(GAS(Asrc + (KT + 1) * 2048),
                                         LAS(Adst + (KT + 1) * 2048), 16, 0, 0);
        __builtin_amdgcn_global_load_lds(GAS(Asrc + (KT + 1) * 2048 + 1024),
                                         LAS(Adst + (KT + 1) * 2048 + 1024), 16, 0, 0);
      }
      if (KT < 7) {
        const unsigned char* Bs = Bbase + (size_t)(ct * 4 + wave) * 16384
                                + (KT + 1) * 2048 + lane * 16;
        unsigned char* bd = lB[(KT + 1) & 1] + wave * 2048 + lane * 16;
        __builtin_amdgcn_global_load_lds(GAS(Bs), LAS(bd), 16, 0, 0);
        __builtin_amdgcn_global_load_lds(GAS(Bs + 1024), LAS(bd + 1024), 16, 0, 0);
      } else if (t + 1 < cnt) {
        const unsigned char* Bs = Bbase + (size_t)((ct + 1) * 4 + wave) * 16384
                                + lane * 16;
        unsigned char* bd = lB[0] + wave * 2048 + lane * 16;   // (KT+1)&1 == 0
        __builtin_amdgcn_global_load_lds(GAS(Bs), LAS(bd), 16, 0, 0);
        __builtin_amdgcn_global_load_lds(GAS(Bs + 1024), LAS(bd + 1024), 16, 0, 0);
      }

      // compute current chunk
      const unsigned char* bufB = lB[KT & 1];
      frag fa[2], fb[2];
#pragma unroll
      for (int i = 0; i < 2; ++i) {
        const int oa = (pa0 + i) * 16384 + KT * 2048 + lfo;
        const int ob = (pb0 + i) * 2048 + lfo;
        fa[i].h[0] = *(const int4*)&lA[oa];
        fa[i].h[1] = *(const int4*)&lA[oa + 512];
        fb[i].h[0] = *(const int4*)&bufB[ob];
        fb[i].h[1] = *(const int4*)&bufB[ob + 512];
      }
#pragma unroll
      for (int mi = 0; mi < 2; ++mi)
#pragma unroll
        for (int ni = 0; ni < 2; ++ni)
          acc[mi][ni] = __builtin_amdgcn_mfma_scale_f32_32x32x64_f8f6f4(
              fa[mi].v, fb[ni].v, acc[mi][ni],
              0, 0,                    // cbsz=e4m3, blgp=e4m3
              0, 0x7F7F7F7F,           // scale_a (E8M0 1.0)
              0, 0x7F7F7F7F);          // scale_b
      __syncthreads();
    }

    // per-tile epilogue: exp, accumulate rowsums in regs, colsum atomics
    float cs[2] = {0.f, 0.f};
#pragma unroll
    for (int mi = 0; mi < 2; ++mi)
#pragma unroll
      for (int ni = 0; ni < 2; ++ni)
#pragma unroll
        for (int rr = 0; rr < 16; ++rr) {
          float v = __expf(2.0f * acc[mi][ni][rr]);
          rs[mi][rr] += v;
          cs[ni] += v;
        }
    const bool diag = (!cross) && (ct == by);
    if (!diag) {
#pragma unroll
      for (int ni = 0; ni < 2; ++ni) {
        float v = cs[ni] + __shfl_xor(cs[ni], 32, 64);
        if (half == 0)
          atomicAdd(&cptr[ct * 128 + (wave >> 1) * 64 + ni * 32 + l31], v);
      }
    }
  }

  // rowsum: reduce over 32 column-lanes, one atomic set per block
#pragma unroll
  for (int mi = 0; mi < 2; ++mi) {
#pragma unroll
    for (int d = 1; d < 32; d <<= 1) {
#pragma unroll
      for (int rr = 0; rr < 16; ++rr) rs[mi][rr] += __shfl_xor(rs[mi][rr], d, 64);
    }
    if (l31 == 0) {
      const int mb = by * 128 + (wave & 1) * 64 + mi * 32;
#pragma unroll
      for (int rr = 0; rr < 16; ++rr) {
        const int row = mb + (rr & 3) + 8 * (rr >> 2) + 4 * half;
        atomicAdd(&rptr[row], rs[mi][rr]);
      }
    }
  }
}

// ------- normalize -> fp8 in 32-row-panel FRAGMENT-MAJOR layout + diag dot -------
__global__ __launch_bounds__(256)
void norm_diag_kernel(const unsigned short* __restrict__ h1,
                      const unsigned short* __restrict__ h2,
                      unsigned char* __restrict__ q1,
                      unsigned char* __restrict__ q2,
                      float* __restrict__ cdiag) {
  const int wave = threadIdx.x >> 6, lane = threadIdx.x & 63;
  const int row = blockIdx.x * 4 + wave;
  const u16x8 u1 = *(const u16x8*)(h1 + (size_t)row * 512 + lane * 8);
  const u16x8 u2 = *(const u16x8*)(h2 + (size_t)row * 512 + lane * 8);
  float f1[8], f2[8], ss1 = 0.f, ss2 = 0.f;
#pragma unroll
  for (int j = 0; j < 8; ++j) {
    f1[j] = bf2f(u1[j]); ss1 += f1[j] * f1[j];
    f2[j] = bf2f(u2[j]); ss2 += f2[j] * f2[j];
  }
#pragma unroll
  for (int d = 1; d < 64; d <<= 1) {
    ss1 += __shfl_xor(ss1, d, 64);
    ss2 += __shfl_xor(ss2, d, 64);
  }
  const float inv1 = 1.0f / fmaxf(sqrtf(ss1), 1e-12f);
  const float inv2 = 1.0f / fmaxf(sqrtf(ss2), 1e-12f);
  float a[8], bb[8];
  float dot = 0.f;
#pragma unroll
  for (int j = 0; j < 8; ++j) {
    a[j] = f1[j] * inv1; bb[j] = f2[j] * inv2;
    dot += a[j] * bb[j];
  }
  int lo1 = __builtin_amdgcn_cvt_pk_fp8_f32(a[0], a[1], 0, false);
  lo1 = __builtin_amdgcn_cvt_pk_fp8_f32(a[2], a[3], lo1, true);
  int hi1 = __builtin_amdgcn_cvt_pk_fp8_f32(a[4], a[5], 0, false);
  hi1 = __builtin_amdgcn_cvt_pk_fp8_f32(a[6], a[7], hi1, true);
  int lo2 = __builtin_amdgcn_cvt_pk_fp8_f32(bb[0], bb[1], 0, false);
  lo2 = __builtin_amdgcn_cvt_pk_fp8_f32(bb[2], bb[3], lo2, true);
  int hi2 = __builtin_amdgcn_cvt_pk_fp8_f32(bb[4], bb[5], 0, false);
  hi2 = __builtin_amdgcn_cvt_pk_fp8_f32(bb[6], bb[7], hi2, true);

  // fragment-major dst: panel = row>>5, 64-col chunk = c0>>6, sub = (c0>>4)&3
  const int c0 = lane * 8;
  const size_t dst = (size_t)(row >> 5) * 16384 + (c0 >> 6) * 2048
                   + ((c0 >> 4) & 3) * 512 + (row & 31) * 16 + (c0 & 15);
  *(int2*)(q1 + dst) = make_int2(lo1, hi1);
  *(int2*)(q2 + dst) = make_int2(lo2, hi2);
#pragma unroll
  for (int d = 1; d < 64; d <<= 1) dot += __shfl_xor(dot, d, 64);
  if (lane == 0) cdiag[row] = dot;
}

// ---------------- final scalar loss ----------------
__global__ __launch_bounds__(256)
void finalize_kernel(const float* __restrict__ d11, const float* __restrict__ d22,
                     const float* __restrict__ d12r, const float* __restrict__ d12c,
                     const float* __restrict__ cdiag, float* __restrict__ out) {
  const float e2 = 7.38905609893065f;
  float s = 0.f;
  for (int i = threadIdx.x; i < 8192; i += 256) {
    const float den1 = d11[i] + d12r[i] - e2;
    const float den2 = d22[i] + d12c[i] - e2;
    s += -2.0f * cdiag[i] + 0.5f * (logf(den1) + logf(den2));
  }
#pragma unroll
  for (int d = 1; d < 64; d <<= 1) s += __shfl_xor(s, d, 64);
  __shared__ float sm[4];
  if ((threadIdx.x & 63) == 0) sm[threadIdx.x >> 6] = s;
  __syncthreads();
  if (threadIdx.x == 0) out[0] = (sm[0] + sm[1] + sm[2] + sm[3]) * (1.0f / 8192.0f);
}

extern "C" void kernel_launch(void* const* d_in, const int* in_sizes, int n_in,
                              void* d_out, int out_size, void* d_ws, size_t ws_size,
                              hipStream_t stream) {
  const float* z1 = (const float*)d_in[0];
  const float* z2 = (const float*)d_in[1];
  const float* w1 = (const float*)d_in[2];
  const float* b1 = (const float*)d_in[3];
  const float* w2 = (const float*)d_in[4];
  const float* b2 = (const float*)d_in[5];
  float* out = (float*)d_out;

  const int N = 8192, D = 512;
  char* ws = (char*)d_ws;
  auto alloc = [&](size_t bytes) {
    char* p = ws; ws += (bytes + 255) & ~(size_t)255; return p;
  };
  unsigned short* h1  = (unsigned short*)alloc((size_t)N * D * 2);  // proj2 out
  unsigned short* h2  = (unsigned short*)alloc((size_t)N * D * 2);
  unsigned short* g1  = (unsigned short*)alloc((size_t)N * D * 2);  // proj1 out
  unsigned short* g2  = (unsigned short*)alloc((size_t)N * D * 2);
  unsigned short* w1b = (unsigned short*)alloc((size_t)D * D * 2);
  unsigned short* w2b = (unsigned short*)alloc((size_t)D * D * 2);
  float* sums  = (float*)alloc((size_t)4 * N * sizeof(float));
  float* cdiag = (float*)alloc((size_t)N * sizeof(float));
  float* d11 = sums, *d22 = sums + N, *d12r = sums + 2 * N, *d12c = sums + 3 * N;
  unsigned char* q1 = (unsigned char*)g1;   // fp8 aliases g (dead after proj2)
  unsigned char* q2 = (unsigned char*)g2;

  hipMemsetAsync(sums, 0, (size_t)4 * N * sizeof(float), stream);

  cast_w_kernel<<<dim3(512), 256, 0, stream>>>(w1, w2, w1b, w2b);
  // proj1 reads z in f32 directly (cast-on-stage)
  proj_kernel<0><<<dim3(512), 256, 0, stream>>>((const void*)z1, (const void*)z2,
                                                w1b, b1, g1, g2);
  proj_kernel<1><<<dim3(512), 256, 0, stream>>>((const void*)g1, (const void*)g2,
                                                w2b, b2, h1, h2);
  norm_diag_kernel<<<dim3(N / 4), 256, 0, stream>>>(h1, h2, q1, q2, cdiag);
  gram_kernel<<<dim3(2112), 256, 0, stream>>>(q1, q2, d11, d22, d12r, d12c);
  finalize_kernel<<<1, 256, 0, stream>>>(d11, d22, d12r, d12c, cdiag, out);
}